// Round 10
// baseline (195.626 us; speedup 1.0000x reference)
//
#include <hip/hip_runtime.h>
#include <cmath>
#include <cstdint>

#define S_LEN 4096
#define NH 16
#define HD 64

typedef _Float16 f16x8 __attribute__((ext_vector_type(8)));
typedef __attribute__((ext_vector_type(4))) float f32x4;
typedef __attribute__((ext_vector_type(16))) float f32x16;
typedef __attribute__((ext_vector_type(4))) unsigned short u16x4;
typedef __attribute__((ext_vector_type(4))) unsigned int u32x4;
typedef int i32x2 __attribute__((ext_vector_type(2)));
typedef __attribute__((ext_vector_type(4))) float f4;

__device__ __forceinline__ unsigned short f2h(float x) {
  union { _Float16 h; unsigned short u; } v; v.h = (_Float16)x; return v.u;
}
__device__ __forceinline__ float h2f(unsigned short u) {
  union { unsigned short u; _Float16 h; } v; v.u = u; return (float)v.h;
}
__device__ __forceinline__ float exp2a(float x) {
  float r; asm("v_exp_f32 %0, %1" : "=v"(r) : "v"(x)); return r;
}
// packs: low16 = f16(a), high16 = f16(b), round-toward-zero
__device__ __forceinline__ unsigned pkh(float a, float b) {
  unsigned r;
  asm("v_cvt_pkrtz_f16_f32 %0, %1, %2" : "=v"(r) : "v"(a), "v"(b));
  return r;
}
__device__ __forceinline__ float max3a(float a, float b, float c) {
  float r;
  asm("v_max3_f32 %0, %1, %2, %3" : "=v"(r) : "v"(a), "v"(b), "v"(c));
  return r;
}
// cross-half partner value via permlane32_swap (no LDS pipe):
__device__ __forceinline__ float swapx32(float v, int hi2) {
  i32x2 r = __builtin_amdgcn_permlane32_swap(__float_as_int(v), __float_as_int(v),
                                             false, false);
  return __int_as_float(hi2 ? r[0] : r[1]);
}

#define GLL16(g, l) __builtin_amdgcn_global_load_lds( \
    (const __attribute__((address_space(1))) void*)(g), \
    (__attribute__((address_space(3))) void*)(l), 16, 0, 0)

// per-head byte size of a swizzled-tile plane: 4096 rows * 128B
#define PLANE_BYTES 524288
// one 64x64 2-byte tile: 8KB
#define TILE_BYTES 8192

// ---------------------------------------------------------------- convert + rope table
__global__ __launch_bounds__(256) void cvt_table_kernel(
    const float* __restrict__ hs, const float* __restrict__ wq,
    const float* __restrict__ wk, const float* __restrict__ wv,
    const float* __restrict__ wo,
    unsigned short* __restrict__ hs16,
    unsigned short* __restrict__ wq16, unsigned short* __restrict__ wk16,
    unsigned short* __restrict__ wv16, unsigned short* __restrict__ wo16,
    float* __restrict__ cosT, float* __restrict__ sinT, double base)
{
  if (blockIdx.x >= 4096) {
    int idx = (blockIdx.x - 4096) * 256 + threadIdx.x;
    if (idx < S_LEN * 32) {
      int t = idx >> 5, j = idx & 31;
      double invf = pow(base, -(double)j / 32.0);
      double f = fmod((double)t * invf, 6.283185307179586476925286766559);
      float ff = (float)f;
      cosT[idx] = cosf(ff);
      sinT[idx] = sinf(ff);
    }
    return;
  }
  const int HID4 = (S_LEN * 1024) / 4;
  const int W4   = (1024 * 1024) / 4;
  const int total = HID4 + 4 * W4;
  for (int i = blockIdx.x * 256 + threadIdx.x; i < total; i += 4096 * 256) {
    const float* s; unsigned short* d; int off;
    if (i < HID4) { s = hs; d = hs16; off = i; }
    else {
      int j = i - HID4; int w = j >> 18; off = j & (W4 - 1);
      s = (w == 0) ? wq : (w == 1) ? wk : (w == 2) ? wv : wo;
      d = (w == 0) ? wq16 : (w == 1) ? wk16 : (w == 2) ? wv16 : wo16;
    }
    f4 v = *(const f4*)(s + (size_t)off * 4);
    u16x4 r;
#pragma unroll
    for (int j = 0; j < 4; j++) r[j] = f2h(v[j]);
    *(u16x4*)(d + (size_t)off * 4) = r;
  }
}

// ---------------------------------------------------------------- fp16 GEMM (NT)
__global__ __launch_bounds__(256) void gemm_f16(
    const unsigned short* __restrict__ A,
    const unsigned short* __restrict__ B0, const unsigned short* __restrict__ B1,
    const unsigned short* __restrict__ B2,
    void* O0, void* O1, void* O2, int M, int K, int fin)
{
  __shared__ unsigned short As[128 * 64];
  __shared__ unsigned short Bs[128 * 64];
  const int z = blockIdx.z;
  const unsigned short* B = (z == 0) ? B0 : (z == 1) ? B1 : B2;
  void* O = (z == 0) ? O0 : (z == 1) ? O1 : O2;
  const int m0 = blockIdx.y * 128, n0 = blockIdx.x * 128;
  const int tid = threadIdx.x, wid = tid >> 6, lane = tid & 63;
  const int lr = lane & 15, lk = (lane >> 4) * 8;
  const int wr = (wid >> 1) * 64, wc = (wid & 1) * 64;
  const int strow = lane >> 3;
  const int stcol = (lane & 7) * 8;

  f32x4 acc[4][4];
#pragma unroll
  for (int m = 0; m < 4; m++)
#pragma unroll
    for (int n = 0; n < 4; n++) acc[m][n] = (f32x4){0.f, 0.f, 0.f, 0.f};

  for (int kt = 0; kt < K; kt += 64) {
#pragma unroll
    for (int i = 0; i < 4; i++) {
      int c = wid * 4 + i;
      int row = c * 8 + strow;
      GLL16(A + (size_t)(m0 + row) * K + kt + stcol, &As[c * 512]);
      GLL16(B + (size_t)(n0 + row) * K + kt + stcol, &Bs[c * 512]);
    }
    __syncthreads();
    f16x8 af[4][2], bfr[4][2];
#pragma unroll
    for (int m = 0; m < 4; m++)
#pragma unroll
      for (int kk = 0; kk < 2; kk++)
        af[m][kk] = *(const f16x8*)&As[(wr + m * 16 + lr) * 64 + kk * 32 + lk];
#pragma unroll
    for (int n = 0; n < 4; n++)
#pragma unroll
      for (int kk = 0; kk < 2; kk++)
        bfr[n][kk] = *(const f16x8*)&Bs[(wc + n * 16 + lr) * 64 + kk * 32 + lk];
#pragma unroll
    for (int m = 0; m < 4; m++)
#pragma unroll
      for (int n = 0; n < 4; n++)
#pragma unroll
        for (int kk = 0; kk < 2; kk++)
          acc[m][n] = __builtin_amdgcn_mfma_f32_16x16x32_f16(
              af[m][kk], bfr[n][kk], acc[m][n], 0, 0, 0);
    __syncthreads();
  }

  const int rbase = m0 + wr + (lane >> 4) * 4;
  const int cbase = n0 + wc + lr;
  if (fin) {
    float* C = (float*)O;
#pragma unroll
    for (int m = 0; m < 4; m++)
#pragma unroll
      for (int n = 0; n < 4; n++)
#pragma unroll
        for (int j = 0; j < 4; j++) {
          int s = rbase + m * 16 + j;
          int o = cbase + n * 16;
          C[(size_t)s * 1024 + o] = acc[m][n][j];
        }
  } else if (z == 2) {
    // V^T swizzled plane, fp16
    char* base = (char*)O;
#pragma unroll
    for (int m = 0; m < 4; m++)
#pragma unroll
      for (int n = 0; n < 4; n++) {
        int s = rbase + m * 16;            // s..s+3, s % 4 == 0
        int o = cbase + n * 16;
        int hd = o >> 6, d = o & 63;
        size_t tb = (size_t)hd * PLANE_BYTES + (size_t)(s >> 6) * TILE_BYTES
                  + (size_t)d * 128;
        int cbyte = (2 * (s & 63)) ^ ((d & 7) << 4);
        u16x4 r;
#pragma unroll
        for (int j = 0; j < 4; j++) r[j] = f2h(acc[m][n][j]);
        *(u16x4*)(base + tb + cbyte) = r;
      }
  } else {
    // Q/K: fp16 [head][s][d]
    unsigned short* C = (unsigned short*)O;
#pragma unroll
    for (int m = 0; m < 4; m++)
#pragma unroll
      for (int n = 0; n < 4; n++)
#pragma unroll
        for (int j = 0; j < 4; j++) {
          int s = rbase + m * 16 + j;
          int o = cbase + n * 16;
          C[((size_t)(o >> 6) * M + s) * HD + (o & 63)] = f2h(acc[m][n][j]);
        }
  }
}

// ---------------------------------------------------------------- rope apply
__global__ __launch_bounds__(256) void rope_apply(
    const unsigned short* __restrict__ Qh, const unsigned short* __restrict__ Kh,
    unsigned short* __restrict__ Q16, char* __restrict__ Kt,
    const float* __restrict__ cosT, const float* __restrict__ sinT)
{
  int wid = threadIdx.x >> 6, lane = threadIdx.x & 63;
  int row = blockIdx.x * 4 + wid;          // 0 .. NH*S_LEN-1, [head][s]
  int t = row & (S_LEN - 1);
  int head = row >> 12;
  int j = (lane < 32) ? lane : (lane - 32);
  float c = cosT[t * 32 + j], s = sinT[t * 32 + j];
  int partner = (lane < 32) ? (2 * lane + 1) : (2 * (lane - 32));
  float sgn = (lane < 32) ? -1.0f : 1.0f;
  float q = h2f(Qh[(size_t)row * HD + lane]);
  float k = h2f(Kh[(size_t)row * HD + lane]);
  float qo = __shfl(q, partner, 64);
  float ko = __shfl(k, partner, 64);
  // fold score scale 8 and log2(e) into Q: softmax in exp2 domain
  float qr = (q * c + sgn * qo * s) * 11.541560327111707f;
  float kr = k * c + sgn * ko * s;
  Q16[(size_t)row * HD + lane] = f2h(qr);
  size_t kb = (size_t)head * PLANE_BYTES + (size_t)(t >> 6) * TILE_BYTES
            + (size_t)(t & 63) * 128 + ((2 * lane) ^ ((t & 7) << 4));
  *(unsigned short*)(Kt + kb) = f2h(kr);
}

// ---------------------------------------------------------------- attention
// Swapped-operand flash attention, fp16 32x32 MFMA, exp2-domain softmax,
// KV-split 2, pipelined, kt-loop unrolled by 2 (compile-time buffers).
// LDS layout per buffer: [0,8K) = K tile, [8K,16K) = V^T tile.
__global__ __launch_bounds__(256, 4) void attn_kernel(
    const unsigned short* __restrict__ Q16, const char* __restrict__ Kt,
    const char* __restrict__ Vt,
    unsigned short* __restrict__ Opart, float* __restrict__ Ml)
{
  __shared__ char LDS[2][16384];

  const int tid = threadIdx.x, wid = tid >> 6, lane = tid & 63;
  const int l5 = lane & 31, hi2 = lane >> 5;
  const int z = blockIdx.z;

  // head->XCD swizzle: heads {x, x+8} live on XCD x
  int id = blockIdx.x + 32 * blockIdx.y;
  int h  = (id & 7) + 8 * ((id >> 3) & 1);
  int bx = id >> 4;
  const int qw = bx * 128 + wid * 32;

  const size_t hoff = (size_t)h * PLANE_BYTES;
  const char* KtH = Kt + hoff;
  const char* VtH = Vt + hoff;

  // per-lane LDS read addresses (byte), hoisted out of the loop:
  // aK[ks] -> K row l5, k-octet ks;  +4096 = K row l5+32;
  // +8192 = V row l5;  +12288 = V row l5+32.
  int aK[4];
#pragma unroll
  for (int ks = 0; ks < 4; ks++)
    aK[ks] = l5 * 128 + ((32 * ks + 16 * hi2) ^ ((l5 & 7) << 4));

  // per-lane staging offsets, hoisted:
  const int swid = wid * 1024;
  const int soff = swid + lane * 16;

  // Q fragments: B-operand, col = q = qw + l5, k-octet d = 16ks + 8hi2 + i
  const unsigned short* Qrow = Q16 + ((size_t)h * S_LEN + qw + l5) * HD;
  f16x8 qf[4];
#pragma unroll
  for (int ks = 0; ks < 4; ks++)
    qf[ks] = *(const f16x8*)&Qrow[ks * 16 + hi2 * 8];

  const f32x16 zf = (f32x16)0.0f;          // persistent zero (never written)
  f32x16 o0 = zf, o1 = zf;
  f32x16 s0, s1;
  float m_q = -__builtin_inff(), l_q = 0.f;

  const int T0 = z * 32;            // first tile of this split
  const int NT = 32;                // tiles per split

#define STAGE(kt, B) do { \
    size_t tb = (size_t)(T0 + (kt)) * TILE_BYTES; \
    const char* gk = KtH + tb; \
    const char* gv = VtH + tb; \
    GLL16(gk + soff,        &LDS[B][swid]); \
    GLL16(gk + soff + 4096, &LDS[B][swid + 4096]); \
    GLL16(gv + soff,        &LDS[B][8192 + swid]); \
    GLL16(gv + soff + 4096, &LDS[B][8192 + swid + 4096]); \
  } while (0)

#define QKT(B) do { \
    __builtin_amdgcn_s_setprio(1); \
    _Pragma("unroll") \
    for (int ks = 0; ks < 4; ks++) { \
      f16x8 k0 = *(const f16x8*)(&LDS[B][aK[ks]]); \
      f16x8 k1 = *(const f16x8*)(&LDS[B][aK[ks] + 4096]); \
      s0 = __builtin_amdgcn_mfma_f32_32x32x16_f16(k0, qf[ks], ks ? s0 : zf, 0, 0, 0); \
      s1 = __builtin_amdgcn_mfma_f32_32x32x16_f16(k1, qf[ks], ks ? s1 : zf, 0, 0, 0); \
    } \
    __builtin_amdgcn_s_setprio(0); \
  } while (0)

// one KV tile: softmax(s) interleaved with PV from buffer CUR;
// then (optionally) QKT(kt+1) from buffer CUR^1; then (optionally) STAGE(kt+2).
#define TILE(kt, CUR, QKN, STG) do { \
    float t0 = max3a(s0[0],  s0[1],  s0[2]); \
    float t1 = max3a(s0[3],  s0[4],  s0[5]); \
    float t2 = max3a(s0[6],  s0[7],  s0[8]); \
    float t3 = max3a(s0[9],  s0[10], s0[11]); \
    float t4 = max3a(s0[12], s0[13], s0[14]); \
    float t5 = max3a(s0[15], s1[0],  s1[1]); \
    float t6 = max3a(s1[2],  s1[3],  s1[4]); \
    float t7 = max3a(s1[5],  s1[6],  s1[7]); \
    float t8 = max3a(s1[8],  s1[9],  s1[10]); \
    float t9 = max3a(s1[11], s1[12], s1[13]); \
    float ta = fmaxf(s1[14], s1[15]); \
    float u0 = max3a(t0, t1, t2); \
    float u1 = max3a(t3, t4, t5); \
    float u2 = max3a(t6, t7, t8); \
    float u3 = fmaxf(t9, ta); \
    float mx = fmaxf(max3a(u0, u1, u2), u3); \
    mx = fmaxf(mx, swapx32(mx, hi2)); \
    if (__any(mx > m_q + 11.0f)) { \
      float mnew = fmaxf(m_q, mx); \
      float alpha = exp2a(m_q - mnew); \
      m_q = mnew; \
      l_q *= alpha; \
      _Pragma("unroll") \
      for (int i = 0; i < 16; i++) { o0[i] *= alpha; o1[i] *= alpha; } \
    } \
    float rs = 0.f; \
    _Pragma("unroll") \
    for (int ks = 0; ks < 4; ks++) { \
      const int base = (ks & 1) * 8; \
      float e0, e1, e2, e3, e4, e5, e6, e7; \
      if (ks < 2) { \
        e0 = exp2a(s0[base + 0] - m_q); e1 = exp2a(s0[base + 1] - m_q); \
        e2 = exp2a(s0[base + 2] - m_q); e3 = exp2a(s0[base + 3] - m_q); \
        e4 = exp2a(s0[base + 4] - m_q); e5 = exp2a(s0[base + 5] - m_q); \
        e6 = exp2a(s0[base + 6] - m_q); e7 = exp2a(s0[base + 7] - m_q); \
      } else { \
        e0 = exp2a(s1[base + 0] - m_q); e1 = exp2a(s1[base + 1] - m_q); \
        e2 = exp2a(s1[base + 2] - m_q); e3 = exp2a(s1[base + 3] - m_q); \
        e4 = exp2a(s1[base + 4] - m_q); e5 = exp2a(s1[base + 5] - m_q); \
        e6 = exp2a(s1[base + 6] - m_q); e7 = exp2a(s1[base + 7] - m_q); \
      } \
      rs += ((e0 + e1) + (e2 + e3)) + ((e4 + e5) + (e6 + e7)); \
      unsigned a0 = pkh(e0, e1); \
      unsigned a1 = pkh(e2, e3); \
      unsigned b0 = pkh(e4, e5); \
      unsigned b1 = pkh(e6, e7); \
      i32x2 r0 = __builtin_amdgcn_permlane32_swap((int)a0, (int)b0, false, false); \
      i32x2 r1 = __builtin_amdgcn_permlane32_swap((int)a1, (int)b1, false, false); \
      u32x4 w; \
      w[0] = (unsigned)r0[0]; \
      w[1] = (unsigned)r1[0]; \
      w[2] = (unsigned)r0[1]; \
      w[3] = (unsigned)r1[1]; \
      union { u32x4 u; f16x8 f; } cv; cv.u = w; \
      f16x8 v0 = *(const f16x8*)(&LDS[CUR][aK[ks] + 8192]); \
      f16x8 v1 = *(const f16x8*)(&LDS[CUR][aK[ks] + 12288]); \
      o0 = __builtin_amdgcn_mfma_f32_32x32x16_f16(v0, cv.f, o0, 0, 0, 0); \
      o1 = __builtin_amdgcn_mfma_f32_32x32x16_f16(v1, cv.f, o1, 0, 0, 0); \
    } \
    rs += swapx32(rs, hi2); \
    l_q += rs; \
    if (QKN) { \
      asm volatile("s_waitcnt vmcnt(0)" ::: "memory"); \
      __builtin_amdgcn_s_barrier(); \
      asm volatile("" ::: "memory"); \
      QKT(CUR ^ 1); \
    } \
    if (STG) { \
      asm volatile("" ::: "memory"); \
      __builtin_amdgcn_s_barrier(); \
      asm volatile("" ::: "memory"); \
      STAGE((kt) + 2, CUR); \
    } \
  } while (0)

  STAGE(0, 0);
  asm volatile("s_waitcnt vmcnt(0)" ::: "memory");
  __builtin_amdgcn_s_barrier();            // buf0 ready
  asm volatile("" ::: "memory");
  STAGE(1, 1);                             // prefetch tile 1 (fresh buffer)
  QKT(0);                                  // scores for tile 0

  for (int kt2 = 0; kt2 < NT - 2; kt2 += 2) {
    TILE(kt2, 0, 1, 1);
    TILE(kt2 + 1, 1, 1, 1);
  }
  TILE(NT - 2, 0, 1, 0);                   // QKT(31), no further staging
  TILE(NT - 1, 1, 0, 0);                   // final tile: softmax+PV only
#undef STAGE
#undef QKT
#undef TILE

  // ---- epilogue: normalized partial fp16 + (m,l) ----
  const float inv = 1.0f / l_q;
  const int q = qw + l5;
  unsigned* orow = (unsigned*)(Opart + (((size_t)(z * NH + h)) * S_LEN + q) * HD);
#pragma unroll
  for (int k = 0; k < 8; k++) {
    const int d0 = 2 * (k & 1) + 8 * (k >> 1) + 4 * hi2;
    orow[d0 >> 1]        = pkh(o0[2 * k] * inv, o0[2 * k + 1] * inv);
    orow[(d0 + 32) >> 1] = pkh(o1[2 * k] * inv, o1[2 * k + 1] * inv);
  }
  if (hi2 == 0) {
    float2* mlp = (float2*)Ml + ((size_t)(z * NH + h)) * S_LEN + q;
    *mlp = make_float2(m_q, l_q);
  }
}

// ---------------------------------------------------------------- combine
__global__ __launch_bounds__(256) void combine_kernel(
    const unsigned short* __restrict__ Opart, const float* __restrict__ Ml,
    unsigned short* __restrict__ Ab)
{
  const int NQ = S_LEN * 1024 / 4;
  for (int idx = blockIdx.x * 256 + threadIdx.x; idx < NQ;
       idx += gridDim.x * 256) {
    int e = idx * 4;
    int s = e >> 10;
    int col = e & 1023;
    int h = col >> 6, d = col & 63;
    const float2* mlb = (const float2*)Ml;
    float2 ml0 = mlb[(size_t)h * S_LEN + s];
    float2 ml1 = mlb[(size_t)(NH + h) * S_LEN + s];
    float mmax = fmaxf(ml0.x, ml1.x);
    float w0 = exp2f(ml0.x - mmax) * ml0.y;
    float w1 = exp2f(ml1.x - mmax) * ml1.y;
    float rden = 1.0f / (w0 + w1);
    float c0 = w0 * rden, c1 = w1 * rden;
    const unsigned short* p0 = Opart + ((size_t)h * S_LEN + s) * HD + d;
    const unsigned short* p1 = Opart + ((size_t)(NH + h) * S_LEN + s) * HD + d;
    u16x4 a = *(const u16x4*)p0;
    u16x4 b = *(const u16x4*)p1;
    u16x4 r;
#pragma unroll
    for (int j = 0; j < 4; j++)
      r[j] = f2h(c0 * h2f(a[j]) + c1 * h2f(b[j]));
    *(u16x4*)(Ab + e) = r;
  }
}

// ---------------------------------------------------------------- launch
extern "C" void kernel_launch(void* const* d_in, const int* in_sizes, int n_in,
                              void* d_out, int out_size, void* d_ws, size_t ws_size,
                              hipStream_t stream)
{
  const float* hs = (const float*)d_in[0];
  const float* Wq = (const float*)d_in[1];
  const float* Wk = (const float*)d_in[2];
  const float* Wv = (const float*)d_in[3];
  const float* Wo = (const float*)d_in[4];

  char* ws = (char*)d_ws;
  const size_t HS = (size_t)S_LEN * 1024;      // 4194304 elems
  const size_t WN = (size_t)1024 * 1024;
  size_t off = 0;
  unsigned short* hs16 = (unsigned short*)(ws + off); off += HS * 2;   // 8MB -> Q16
  unsigned short* wq16 = (unsigned short*)(ws + off); off += WN * 2;
  unsigned short* wk16 = (unsigned short*)(ws + off); off += WN * 2;
  unsigned short* wv16 = (unsigned short*)(ws + off); off += WN * 2;
  unsigned short* wo16 = (unsigned short*)(ws + off); off += WN * 2;
  unsigned short* Qh16 = (unsigned short*)(ws + off); off += HS * 2;   // 8MB \ -> Opart
  unsigned short* Kh16 = (unsigned short*)(ws + off); off += HS * 2;   // 8MB /  (16MB)
  char* Kt_g = ws + off; off += (size_t)NH * PLANE_BYTES;              // 8MB
  char* VT_g = ws + off; off += (size_t)NH * PLANE_BYTES;              // 8MB
  unsigned short* Ab = (unsigned short*)(ws + off); off += HS * 2;     // 8MB
  float* Ml = (float*)(ws + off); off += (size_t)2 * NH * S_LEN * 8;   // 1MB
  float* cosT = (float*)(ws + off); off += (size_t)S_LEN * 32 * 4;
  float* sinT = (float*)(ws + off); off += (size_t)S_LEN * 32 * 4;
  // aliases (regions dead by the time they're written):
  unsigned short* Q16 = hs16;              // hs16 dead after QKV gemm
  unsigned short* Opart = Qh16;            // Qh16+Kh16 dead after rope_apply

  double base = 10000.0 * pow((double)S_LEN / 2048.0, 64.0 / 62.0);

  cvt_table_kernel<<<4608, 256, 0, stream>>>(hs, Wq, Wk, Wv, Wo,
                                             hs16, wq16, wk16, wv16, wo16,
                                             cosT, sinT, base);

  gemm_f16<<<dim3(8, 32, 3), 256, 0, stream>>>(
      hs16, wq16, wk16, wv16, Qh16, Kh16, VT_g, S_LEN, 1024, 0);

  rope_apply<<<NH * S_LEN / 4, 256, 0, stream>>>(
      Qh16, Kh16, Q16, Kt_g, cosT, sinT);

  attn_kernel<<<dim3(32, 16, 2), 256, 0, stream>>>(
      Q16, Kt_g, VT_g, Opart, Ml);

  combine_kernel<<<2048, 256, 0, stream>>>(Opart, Ml, Ab);

  gemm_f16<<<dim3(8, 32, 1), 256, 0, stream>>>(
      Ab, wo16, wo16, wo16, d_out, d_out, d_out, S_LEN, 1024, 1);
}